// Round 2
// baseline (5961.808 us; speedup 1.0000x reference)
//
#include <hip/hip_runtime.h>
#include <math.h>

// SentenceDecoder: B=64, D=512, H=1024, V=32000, L=2, T=32. NG = 4H = 4096.
#define BB 64
#define DD 512
#define HH 1024
#define VV 32000
#define NG 4096
#define TT 32
#define KS 8              // K-split for fused gate GEMM
#define VBLK 500          // V / 64 logits tiles

typedef __bf16 bf16x8 __attribute__((ext_vector_type(8)));
typedef float  f32x4  __attribute__((ext_vector_type(4)));

// split fp32 into bf16 hi + bf16 lo (RN-even both): x ~= hi + lo, err ~2^-17 rel
__device__ __forceinline__ void split_bf16(float x, unsigned short* hi, unsigned short* lo)
{
    unsigned u = __float_as_uint(x);
    unsigned r = (u + 0x7fffu + ((u >> 16) & 1u)) & 0xffff0000u;
    *hi = (unsigned short)(r >> 16);
    float rem = x - __uint_as_float(r);
    unsigned u2 = __float_as_uint(rem);
    unsigned r2 = u2 + 0x7fffu + ((u2 >> 16) & 1u);
    *lo = (unsigned short)(r2 >> 16);
}

// ---------------------------------------------------------------------------
// split_k: fp32 array -> bf16 hi/lo arrays (one-time: Wout, features)
// ---------------------------------------------------------------------------
__global__ __launch_bounds__(256)
void split_k(const float* __restrict__ src, unsigned short* __restrict__ hi,
             unsigned short* __restrict__ lo, int n4)
{
    const int stride = gridDim.x * 256;
    for (int i = blockIdx.x * 256 + threadIdx.x; i < n4; i += stride) {
        const float4 v = ((const float4*)src)[i];
        ushort4 h, l;
        split_bf16(v.x, &h.x, &l.x);
        split_bf16(v.y, &h.y, &l.y);
        split_bf16(v.z, &h.z, &l.z);
        split_bf16(v.w, &h.w, &l.w);
        ((ushort4*)hi)[i] = h;
        ((ushort4*)lo)[i] = l;
    }
}

// ---------------------------------------------------------------------------
// split_gate_k: gate weight fp32 (row g*H+u) -> bf16 hi/lo with rows
// INTERLEAVED as r' = 4u+g, so a 64-col tile covers 16 complete units.
// kshift: log2(K/4) (K = row length in fp32).
// ---------------------------------------------------------------------------
__global__ __launch_bounds__(256)
void split_gate_k(const float* __restrict__ src, unsigned short* __restrict__ hi,
                  unsigned short* __restrict__ lo, int kshift, int n4)
{
    const int stride = gridDim.x * 256;
    const int K4m = (1 << kshift) - 1;
    for (int i = blockIdx.x * 256 + threadIdx.x; i < n4; i += stride) {
        const int r = i >> kshift;          // interleaved row r' = 4u+g
        const int k4 = i & K4m;
        const int u = r >> 2, g = r & 3;
        const float4 v = ((const float4*)src)[((size_t)(g * HH + u) << kshift) + k4];
        ushort4 h, l;
        split_bf16(v.x, &h.x, &l.x);
        split_bf16(v.y, &h.y, &l.y);
        split_bf16(v.z, &h.z, &l.z);
        split_bf16(v.w, &h.w, &l.w);
        ((ushort4*)hi)[i] = h;
        ((ushort4*)lo)[i] = l;
    }
}

// ---------------------------------------------------------------------------
// bias_k: bsum[4u+g] = bih[g*H+u] + bhh[g*H+u]  (interleaved gate bias)
// ---------------------------------------------------------------------------
__global__ __launch_bounds__(256)
void bias_k(const float* __restrict__ bih, const float* __restrict__ bhh,
            float* __restrict__ bsum)
{
    const int r = blockIdx.x * 256 + threadIdx.x;    // 0..NG-1
    const int u = r >> 2, g = r & 3;
    bsum[r] = bih[g * HH + u] + bhh[g * HH + u];
}

// ---------------------------------------------------------------------------
// gatescell_k: fused dual GEMM (split-bf16 MFMA) + LSTM cell epilogue.
//   P[y][b][j'] = sum_{k in y-chunk} A0[b][k]*Wih[j'][k] + A1[b][k]*Whh[j'][k]
// Grid (64 tiles, KS). W rows interleaved (j' = 4u+g). The LAST y-slice of
// each tile (atomic ticket) sums the KS partials + bias and runs the cell for
// its 16 units x 64 batches, writing h hi/lo (ping-pong buffer) and c.
// ---------------------------------------------------------------------------
__global__ __launch_bounds__(256)
void gatescell_k(const unsigned short* __restrict__ Ahi0, const unsigned short* __restrict__ Alo0,
                 const int K0,
                 const unsigned short* __restrict__ Ahi1, const unsigned short* __restrict__ Alo1,
                 const unsigned short* __restrict__ Wihi, const unsigned short* __restrict__ Wilo,
                 const unsigned short* __restrict__ Whhi, const unsigned short* __restrict__ Whlo,
                 const float* __restrict__ bsum, float* __restrict__ c,
                 unsigned short* __restrict__ Hhi, unsigned short* __restrict__ Hlo,
                 float* __restrict__ P, int* __restrict__ cnt)
{
    // stride 72 bf16 = 144 B per row: 16B-aligned, only 2-way bank aliasing
    __shared__ unsigned short Ah[64][72], Al[64][72], Wh[64][72], Wl[64][72];
    __shared__ int s_last;

    const int j0   = blockIdx.x * 64;
    const int y    = blockIdx.y;
    const int tid  = threadIdx.x;
    const int wv   = tid >> 6;        // wave id 0..3 -> m rows 16*wv..
    const int lane = tid & 63;
    const int l15  = lane & 15;
    const int q    = lane >> 4;       // quad 0..3
    const int sr   = tid >> 3;        // staging row 0..31
    const int sc   = tid & 7;         // staging 8-bf16 chunk

    f32x4 acc[4] = {{0,0,0,0},{0,0,0,0},{0,0,0,0},{0,0,0,0}};

#pragma unroll
    for (int seg = 0; seg < 2; seg++) {
        const unsigned short* __restrict__ Ahi = seg ? Ahi1 : Ahi0;
        const unsigned short* __restrict__ Alo = seg ? Alo1 : Alo0;
        const unsigned short* __restrict__ Whi = seg ? Whhi : Wihi;
        const unsigned short* __restrict__ Wlo = seg ? Whlo : Wilo;
        const int K  = seg ? HH : K0;
        const int kc = K >> 3;         // K0=512 -> 64, 1024 -> 128
        const int kend = y * kc + kc;

        for (int kb = y * kc; kb < kend; kb += 64) {
#pragma unroll
            for (int qq = 0; qq < 2; qq++) {
                const int row = sr + 32 * qq;
                *(uint4*)&Ah[row][sc * 8] = *(const uint4*)(Ahi + (size_t)row * K + kb + sc * 8);
                *(uint4*)&Al[row][sc * 8] = *(const uint4*)(Alo + (size_t)row * K + kb + sc * 8);
                *(uint4*)&Wh[row][sc * 8] = *(const uint4*)(Whi + (size_t)(j0 + row) * K + kb + sc * 8);
                *(uint4*)&Wl[row][sc * 8] = *(const uint4*)(Wlo + (size_t)(j0 + row) * K + kb + sc * 8);
            }
            __syncthreads();
#pragma unroll
            for (int ks = 0; ks < 2; ks++) {
                const int ko = ks * 32 + q * 8;
                const bf16x8 ah = *(const bf16x8*)&Ah[16 * wv + l15][ko];
                const bf16x8 al = *(const bf16x8*)&Al[16 * wv + l15][ko];
#pragma unroll
                for (int t = 0; t < 4; t++) {
                    const bf16x8 bh = *(const bf16x8*)&Wh[16 * t + l15][ko];
                    const bf16x8 bl = *(const bf16x8*)&Wl[16 * t + l15][ko];
                    acc[t] = __builtin_amdgcn_mfma_f32_16x16x32_bf16(ah, bl, acc[t], 0, 0, 0);
                    acc[t] = __builtin_amdgcn_mfma_f32_16x16x32_bf16(al, bh, acc[t], 0, 0, 0);
                    acc[t] = __builtin_amdgcn_mfma_f32_16x16x32_bf16(ah, bh, acc[t], 0, 0, 0);
                }
            }
            __syncthreads();
        }
    }

    // C/D layout (16x16): col = lane&15, row = q*4 + reg  [m89-verified]
    float* __restrict__ Pout = P + (size_t)y * (BB * NG);
#pragma unroll
    for (int reg = 0; reg < 4; reg++) {
        const int row = 16 * wv + q * 4 + reg;     // batch index
#pragma unroll
        for (int t = 0; t < 4; t++)
            Pout[(size_t)row * NG + j0 + 16 * t + l15] = acc[t][reg];
    }

    // ticket: last y-slice of this tile runs the cell epilogue
    __syncthreads();
    if (tid == 0) {
        const int prev = __hip_atomic_fetch_add(cnt + blockIdx.x, 1,
                                                __ATOMIC_ACQ_REL, __HIP_MEMORY_SCOPE_AGENT);
        s_last = (prev == KS - 1);
    }
    __syncthreads();
    if (!s_last) return;
    if (tid == 0)
        __hip_atomic_store(cnt + blockIdx.x, 0, __ATOMIC_RELAXED, __HIP_MEMORY_SCOPE_AGENT);

    const int u0 = blockIdx.x * 16;                // first unit of this tile
#pragma unroll
    for (int p = 0; p < 4; p++) {
        const int idx = tid + 256 * p;             // 0..1023 = (b, ui)
        const int b = idx >> 4;
        const int u = u0 + (idx & 15);
        float4 g = *(const float4*)&bsum[4 * u];   // (i,f,g,o) for unit u
#pragma unroll
        for (int s = 0; s < KS; s++) {
            const float4 p4 = *(const float4*)&P[(size_t)s * (BB * NG) + (size_t)b * NG + 4 * u];
            g.x += p4.x; g.y += p4.y; g.z += p4.z; g.w += p4.w;
        }
        const float si = 1.0f / (1.0f + expf(-g.x));
        const float sf = 1.0f / (1.0f + expf(-g.y));
        const float so = 1.0f / (1.0f + expf(-g.w));
        const float cn = sf * c[b * HH + u] + si * tanhf(g.z);
        const float hn = so * tanhf(cn);
        c[b * HH + u] = cn;
        split_bf16(hn, &Hhi[b * HH + u], &Hlo[b * HH + u]);
    }
}

// ---------------------------------------------------------------------------
// logitsfinal_k: 64x64 logits tile via split-bf16 MFMA + argmax partials;
// the LAST block (atomic ticket) reduces all partials, writes tokens, and
// gathers+splits the embedding rows for the next step.
// ---------------------------------------------------------------------------
__global__ __launch_bounds__(256)
void logitsfinal_k(const unsigned short* __restrict__ Ahi,
                   const unsigned short* __restrict__ Alo,
                   const unsigned short* __restrict__ Whi,
                   const unsigned short* __restrict__ Wlo,
                   const float* __restrict__ bout,
                   float* __restrict__ pv, int* __restrict__ pi,
                   const float* __restrict__ embed,
                   unsigned short* __restrict__ xhi, unsigned short* __restrict__ xlo,
                   int* __restrict__ out, const int t, int* __restrict__ cnt)
{
    __shared__ unsigned short Ah[64][72], Al[64][72], Wh[64][72], Wl[64][72];
    __shared__ float rv[64][16];
    __shared__ int   ri[64][16];
    __shared__ float fv[256];
    __shared__ int   fi[256];
    __shared__ int   s_tok[64];
    __shared__ int   s_last;

    const int v0   = blockIdx.x * 64;
    const int tid  = threadIdx.x;
    const int wv   = tid >> 6;
    const int lane = tid & 63;
    const int l15  = lane & 15;
    const int q    = lane >> 4;
    const int sr   = tid >> 3;
    const int sc   = tid & 7;

    f32x4 acc[4] = {{0,0,0,0},{0,0,0,0},{0,0,0,0},{0,0,0,0}};

    for (int kb = 0; kb < HH; kb += 64) {
#pragma unroll
        for (int qq = 0; qq < 2; qq++) {
            const int row = sr + 32 * qq;
            *(uint4*)&Ah[row][sc * 8] = *(const uint4*)(Ahi + (size_t)row * HH + kb + sc * 8);
            *(uint4*)&Al[row][sc * 8] = *(const uint4*)(Alo + (size_t)row * HH + kb + sc * 8);
            *(uint4*)&Wh[row][sc * 8] = *(const uint4*)(Whi + (size_t)(v0 + row) * HH + kb + sc * 8);
            *(uint4*)&Wl[row][sc * 8] = *(const uint4*)(Wlo + (size_t)(v0 + row) * HH + kb + sc * 8);
        }
        __syncthreads();

#pragma unroll
        for (int ks = 0; ks < 2; ks++) {
            const int ko = ks * 32 + q * 8;
            const bf16x8 ah = *(const bf16x8*)&Ah[16 * wv + l15][ko];
            const bf16x8 al = *(const bf16x8*)&Al[16 * wv + l15][ko];
#pragma unroll
            for (int tt = 0; tt < 4; tt++) {
                const bf16x8 bh = *(const bf16x8*)&Wh[16 * tt + l15][ko];
                const bf16x8 bl = *(const bf16x8*)&Wl[16 * tt + l15][ko];
                acc[tt] = __builtin_amdgcn_mfma_f32_16x16x32_bf16(ah, bl, acc[tt], 0, 0, 0);
                acc[tt] = __builtin_amdgcn_mfma_f32_16x16x32_bf16(al, bh, acc[tt], 0, 0, 0);
                acc[tt] = __builtin_amdgcn_mfma_f32_16x16x32_bf16(ah, bh, acc[tt], 0, 0, 0);
            }
        }
        __syncthreads();
    }

    // epilogue: +bias, per-lane argmax over its 4 cols per row, then LDS reduce.
#pragma unroll
    for (int reg = 0; reg < 4; reg++) {
        float best = -INFINITY;
        int bid = 0x7fffffff;
#pragma unroll
        for (int tt = 0; tt < 4; tt++) {
            const int id = v0 + 16 * tt + l15;
            const float v = acc[tt][reg] + bout[id];
            if (v > best || (v == best && id < bid)) { best = v; bid = id; }
        }
        rv[16 * wv + q * 4 + reg][l15] = best;
        ri[16 * wv + q * 4 + reg][l15] = bid;
    }
    __syncthreads();

    if (tid < 64) {
        float best = -INFINITY;
        int bid = 0x7fffffff;
        for (int k = 0; k < 16; k++) {
            const float v = rv[tid][k];
            const int id = ri[tid][k];
            if (v > best || (v == best && id < bid)) { best = v; bid = id; }
        }
        pv[(size_t)tid * VBLK + blockIdx.x] = best;
        pi[(size_t)tid * VBLK + blockIdx.x] = bid;
    }

    // ticket: last block does the global argmax + embed gather
    __syncthreads();
    if (tid == 0) {
        const int prev = __hip_atomic_fetch_add(cnt, 1,
                                                __ATOMIC_ACQ_REL, __HIP_MEMORY_SCOPE_AGENT);
        s_last = (prev == (int)gridDim.x - 1);
    }
    __syncthreads();
    if (!s_last) return;
    if (tid == 0)
        __hip_atomic_store(cnt, 0, __ATOMIC_RELAXED, __HIP_MEMORY_SCOPE_AGENT);

    // 4 threads per batch row reduce VBLK partials (lexicographic max, id-min)
    {
        const int row = tid >> 2, pt = tid & 3;
        float best = -INFINITY;
        int bid = 0x7fffffff;
        for (int k = pt; k < VBLK; k += 4) {
            const float v = pv[(size_t)row * VBLK + k];
            const int id = pi[(size_t)row * VBLK + k];
            if (v > best || (v == best && id < bid)) { best = v; bid = id; }
        }
        fv[tid] = best; fi[tid] = bid;
    }
    __syncthreads();
    if ((tid & 3) == 0) {
        const int row = tid >> 2;
        float best = fv[tid]; int bid = fi[tid];
#pragma unroll
        for (int j = 1; j < 4; j++) {
            const float v = fv[tid + j]; const int id = fi[tid + j];
            if (v > best || (v == best && id < bid)) { best = v; bid = id; }
        }
        out[(size_t)row * TT + t] = bid;
        s_tok[row] = bid;
    }
    __syncthreads();

    // embed gather + split: 64 rows x 128 float4
    for (int i = tid; i < BB * (DD / 4); i += 256) {
        const int b = i >> 7, d4 = i & 127;
        const float4 e = ((const float4*)(embed + (size_t)s_tok[b] * DD))[d4];
        ushort4 h4, l4;
        split_bf16(e.x, &h4.x, &l4.x);
        split_bf16(e.y, &h4.y, &l4.y);
        split_bf16(e.z, &h4.z, &l4.z);
        split_bf16(e.w, &h4.w, &l4.w);
        *(ushort4*)&xhi[(size_t)b * DD + d4 * 4] = h4;
        *(ushort4*)&xlo[(size_t)b * DD + d4 * 4] = l4;
    }
}

// ---------------------------------------------------------------------------
extern "C" void kernel_launch(void* const* d_in, const int* in_sizes, int n_in,
                              void* d_out, int out_size, void* d_ws, size_t ws_size,
                              hipStream_t stream)
{
    const float* features = (const float*)d_in[0];
    const float* embed    = (const float*)d_in[1];
    const float* Wih0     = (const float*)d_in[2];
    const float* Whh0     = (const float*)d_in[3];
    const float* bih0     = (const float*)d_in[4];
    const float* bhh0     = (const float*)d_in[5];
    const float* Wih1     = (const float*)d_in[6];
    const float* Whh1     = (const float*)d_in[7];
    const float* bih1     = (const float*)d_in[8];
    const float* bhh1     = (const float*)d_in[9];
    const float* Wout     = (const float*)d_in[10];
    const float* bout     = (const float*)d_in[11];
    int* out = (int*)d_out;

    const size_t BH = (size_t)BB * HH;

    // workspace layout (all offsets 16B-aligned)
    float* ws = (float*)d_ws;
    float* c0 = ws;                                            // B*H fp32
    float* c1 = c0 + BH;
    unsigned short* hbuf = (unsigned short*)(c1 + BH);         // 8 x B*H bf16
    unsigned short* xhi  = hbuf + 8 * BH;                      // B*D bf16 each
    unsigned short* xlo  = xhi + (size_t)BB * DD;
    int* cnt = (int*)(xlo + (size_t)BB * DD);                  // 256 ints (zeroed)
    float* part = (float*)((char*)cnt + 1024);                 // KS*B*NG fp32
    float* pv   = part + (size_t)KS * BB * NG;                 // B*VBLK
    int*   pi   = (int*)(pv + (size_t)BB * VBLK);              // B*VBLK
    float* bsum0 = (float*)(pi + (size_t)BB * VBLK);           // NG each
    float* bsum1 = bsum0 + NG;
    unsigned short* wih0h = (unsigned short*)(bsum1 + NG);     // NG*D each (interleaved)
    unsigned short* wih0l = wih0h + (size_t)NG * DD;
    unsigned short* whh0h = wih0l + (size_t)NG * DD;           // NG*H each
    unsigned short* whh0l = whh0h + (size_t)NG * HH;
    unsigned short* wih1h = whh0l + (size_t)NG * HH;
    unsigned short* wih1l = wih1h + (size_t)NG * HH;
    unsigned short* whh1h = wih1l + (size_t)NG * HH;
    unsigned short* whh1l = whh1h + (size_t)NG * HH;
    unsigned short* wouth = whh1l + (size_t)NG * HH;           // V*H each (plain rows)
    unsigned short* woutl = wouth + (size_t)VV * HH;

    // zero c0,c1 + h ping-pong buffers + x + counters (contiguous span)
    const size_t zlen = 2 * BH * sizeof(float) + 8 * BH * sizeof(unsigned short)
                      + 2 * (size_t)BB * DD * sizeof(unsigned short) + 1024;
    hipMemsetAsync(c0, 0, zlen, stream);

    const dim3 blk(256);
    const dim3 ggates(NG / 64, KS);
    const dim3 glog(VBLK);

    // one-time per call: pre-split all constant operands
    {
        auto gs = [](int n4) { int g = (n4 + 255) / 256; return dim3(g > 2048 ? 2048 : g); };
        split_gate_k<<<gs(NG * DD / 4), blk, 0, stream>>>(Wih0, wih0h, wih0l, 7, NG * DD / 4);
        split_gate_k<<<gs(NG * HH / 4), blk, 0, stream>>>(Whh0, whh0h, whh0l, 8, NG * HH / 4);
        split_gate_k<<<gs(NG * HH / 4), blk, 0, stream>>>(Wih1, wih1h, wih1l, 8, NG * HH / 4);
        split_gate_k<<<gs(NG * HH / 4), blk, 0, stream>>>(Whh1, whh1h, whh1l, 8, NG * HH / 4);
        split_k<<<gs(VV * HH / 4), blk, 0, stream>>>(Wout, wouth, woutl, VV * HH / 4);
        split_k<<<gs(BB * DD / 4), blk, 0, stream>>>(features, xhi, xlo, BB * DD / 4);
        bias_k<<<dim3(NG / 256), blk, 0, stream>>>(bih0, bhh0, bsum0);
        bias_k<<<dim3(NG / 256), blk, 0, stream>>>(bih1, bhh1, bsum1);
    }

    // h buffer helper: layer l (0/1), ping-pong p (0/1), comp (0=hi,1=lo)
    auto hp = [&](int l, int p, int comp) {
        return hbuf + (((size_t)(l * 2 + p)) * 2 + comp) * BH;
    };

    for (int t = 0; t < TT; t++) {
        const int pp = t & 1;
        // layer 0: gates = x@Wih0^T + h0_prev@Whh0^T, cell fused in epilogue
        gatescell_k<<<ggates, blk, 0, stream>>>(
            xhi, xlo, DD, hp(0, pp, 0), hp(0, pp, 1),
            wih0h, wih0l, whh0h, whh0l, bsum0, c0,
            hp(0, pp ^ 1, 0), hp(0, pp ^ 1, 1), part, cnt);
        // layer 1: gates = h0_new@Wih1^T + h1_prev@Whh1^T
        gatescell_k<<<ggates, blk, 0, stream>>>(
            hp(0, pp ^ 1, 0), hp(0, pp ^ 1, 1), HH, hp(1, pp, 0), hp(1, pp, 1),
            wih1h, wih1l, whh1h, whh1l, bsum1, c1,
            hp(1, pp ^ 1, 0), hp(1, pp ^ 1, 1), part, cnt + 64);
        // output projection + argmax + token write + embed gather (fused)
        logitsfinal_k<<<glog, blk, 0, stream>>>(
            hp(1, pp ^ 1, 0), hp(1, pp ^ 1, 1), wouth, woutl, bout,
            pv, pi, embed, xhi, xlo, out, t, cnt + 128);
    }
}

// Round 3
// 2074.858 us; speedup vs baseline: 2.8734x; 2.8734x over previous
//
#include <hip/hip_runtime.h>
#include <math.h>

// SentenceDecoder: B=64, D=512, H=1024, V=32000, L=2, T=32. NG = 4H = 4096.
#define BB 64
#define DD 512
#define HH 1024
#define VV 32000
#define NG 4096
#define TT 32
#define KS 8              // K-split for fused gate GEMM
#define VBLK 500          // V / 64 logits tiles

typedef __bf16 bf16x8 __attribute__((ext_vector_type(8)));
typedef float  f32x4  __attribute__((ext_vector_type(4)));

// split fp32 into bf16 hi + bf16 lo (RN-even both): x ~= hi + lo, err ~2^-17 rel
__device__ __forceinline__ void split_bf16(float x, unsigned short* hi, unsigned short* lo)
{
    unsigned u = __float_as_uint(x);
    unsigned r = (u + 0x7fffu + ((u >> 16) & 1u)) & 0xffff0000u;
    *hi = (unsigned short)(r >> 16);
    float rem = x - __uint_as_float(r);
    unsigned u2 = __float_as_uint(rem);
    unsigned r2 = u2 + 0x7fffu + ((u2 >> 16) & 1u);
    *lo = (unsigned short)(r2 >> 16);
}

// ---------------------------------------------------------------------------
// split_k: fp32 array -> bf16 hi/lo arrays (one-time per call, weights + feat)
// ---------------------------------------------------------------------------
__global__ __launch_bounds__(256)
void split_k(const float* __restrict__ src, unsigned short* __restrict__ hi,
             unsigned short* __restrict__ lo, int n4)
{
    const int stride = gridDim.x * 256;
    for (int i = blockIdx.x * 256 + threadIdx.x; i < n4; i += stride) {
        const float4 v = ((const float4*)src)[i];
        ushort4 h, l;
        split_bf16(v.x, &h.x, &l.x);
        split_bf16(v.y, &h.y, &l.y);
        split_bf16(v.z, &h.z, &l.z);
        split_bf16(v.w, &h.w, &l.w);
        ((ushort4*)hi)[i] = h;
        ((ushort4*)lo)[i] = l;
    }
}

// ---------------------------------------------------------------------------
// gates_mfma_k: fused dual GEMM via split-bf16 MFMA, register-prefetch
// software pipeline (issue next K-chunk's global loads BEFORE the barrier so
// HBM/L2 latency hides under the MFMA phase; no device-scope atomics).
//   P[y][b][j] = sum_{k in y-chunk} X[b][k]*Wih[j][k] + H[b][k]*Whh[j][k]
// 64x64 tile per block, 256 thr (4 waves), grid (NG/64, KS) = (64, 8).
// ---------------------------------------------------------------------------
__global__ __launch_bounds__(256)
void gates_mfma_k(const unsigned short* __restrict__ Ahi0, const unsigned short* __restrict__ Alo0,
                  const int K0,
                  const unsigned short* __restrict__ Ahi1, const unsigned short* __restrict__ Alo1,
                  const unsigned short* __restrict__ Wihhi, const unsigned short* __restrict__ Wihlo,
                  const unsigned short* __restrict__ Whhhi, const unsigned short* __restrict__ Whhlo,
                  float* __restrict__ P)
{
    // stride 72 bf16 = 144 B per row: 16B-aligned, only 2-way bank aliasing
    __shared__ unsigned short Ah[64][72], Al[64][72], Wh[64][72], Wl[64][72];

    const int j0   = blockIdx.x * 64;
    const int y    = blockIdx.y;
    const int tid  = threadIdx.x;
    const int wv   = tid >> 6;        // wave id 0..3 -> m rows 16*wv..
    const int lane = tid & 63;
    const int l15  = lane & 15;
    const int q    = lane >> 4;       // quad 0..3
    const int sr   = tid >> 3;        // staging row 0..31
    const int sc   = tid & 7;         // staging 8-bf16 chunk

    f32x4 acc[4] = {{0,0,0,0},{0,0,0,0},{0,0,0,0},{0,0,0,0}};

    // flat chunk schedule: seg0 (X/Wih, K=K0) then seg1 (H/Whh, K=HH),
    // 64-wide chunks within this block's y-slice of each segment.
    const int n0 = K0 >> 9;           // K0/512 chunks in seg0 (kc0/64)
    const int nc = n0 + (HH >> 9);    // + HH/512 chunks in seg1

    uint4 rA0h, rA0l, rA1h, rA1l, rW0h, rW0l, rW1h, rW1l;   // in-flight chunk

#define G_LOAD_CHUNK(cc)                                                        \
    do {                                                                        \
        const int seg_ = ((cc) >= n0);                                          \
        const unsigned short* Ah_ = seg_ ? Ahi1 : Ahi0;                         \
        const unsigned short* Al_ = seg_ ? Alo1 : Alo0;                         \
        const unsigned short* Wh_ = seg_ ? Whhhi : Wihhi;                       \
        const unsigned short* Wl_ = seg_ ? Whhlo : Wihlo;                       \
        const int K_ = seg_ ? HH : K0;                                          \
        const int kb_ = y * (K_ >> 3) + ((cc) - (seg_ ? n0 : 0)) * 64;          \
        const size_t ao_ = (size_t)sr * K_ + kb_ + sc * 8;                      \
        const size_t wo_ = (size_t)(j0 + sr) * K_ + kb_ + sc * 8;               \
        const size_t s32_ = (size_t)32 * K_;                                    \
        rA0h = *(const uint4*)(Ah_ + ao_);                                      \
        rA0l = *(const uint4*)(Al_ + ao_);                                      \
        rA1h = *(const uint4*)(Ah_ + ao_ + s32_);                               \
        rA1l = *(const uint4*)(Al_ + ao_ + s32_);                               \
        rW0h = *(const uint4*)(Wh_ + wo_);                                      \
        rW0l = *(const uint4*)(Wl_ + wo_);                                      \
        rW1h = *(const uint4*)(Wh_ + wo_ + s32_);                               \
        rW1l = *(const uint4*)(Wl_ + wo_ + s32_);                               \
    } while (0)

    G_LOAD_CHUNK(0);
    for (int c = 0; c < nc; ++c) {
        if (c) __syncthreads();            // prev compute done reading LDS
        *(uint4*)&Ah[sr][sc * 8]      = rA0h;
        *(uint4*)&Al[sr][sc * 8]      = rA0l;
        *(uint4*)&Ah[sr + 32][sc * 8] = rA1h;
        *(uint4*)&Al[sr + 32][sc * 8] = rA1l;
        *(uint4*)&Wh[sr][sc * 8]      = rW0h;
        *(uint4*)&Wl[sr][sc * 8]      = rW0l;
        *(uint4*)&Wh[sr + 32][sc * 8] = rW1h;
        *(uint4*)&Wl[sr + 32][sc * 8] = rW1l;
        if (c + 1 < nc) G_LOAD_CHUNK(c + 1);   // issue early: hides under MFMA
        __syncthreads();

#pragma unroll
        for (int ks = 0; ks < 2; ks++) {
            const int ko = ks * 32 + q * 8;
            const bf16x8 ah = *(const bf16x8*)&Ah[16 * wv + l15][ko];
            const bf16x8 al = *(const bf16x8*)&Al[16 * wv + l15][ko];
#pragma unroll
            for (int t = 0; t < 4; t++) {
                const bf16x8 bh = *(const bf16x8*)&Wh[16 * t + l15][ko];
                const bf16x8 bl = *(const bf16x8*)&Wl[16 * t + l15][ko];
                acc[t] = __builtin_amdgcn_mfma_f32_16x16x32_bf16(ah, bl, acc[t], 0, 0, 0);
                acc[t] = __builtin_amdgcn_mfma_f32_16x16x32_bf16(al, bh, acc[t], 0, 0, 0);
                acc[t] = __builtin_amdgcn_mfma_f32_16x16x32_bf16(ah, bh, acc[t], 0, 0, 0);
            }
        }
    }
#undef G_LOAD_CHUNK

    // C/D layout (16x16): col = lane&15, row = q*4 + reg  [m89-verified]
    float* __restrict__ Pout = P + (size_t)y * (BB * NG);
#pragma unroll
    for (int reg = 0; reg < 4; reg++) {
        const int row = 16 * wv + q * 4 + reg;     // batch index
#pragma unroll
        for (int t = 0; t < 4; t++)
            Pout[(size_t)row * NG + j0 + 16 * t + l15] = acc[t][reg];
    }
}

// ---------------------------------------------------------------------------
// cell_k: sum KS partial slices + biases -> gates; LSTM cell; emit bf16 hi/lo
// split of h (the only consumed form of h). c stays fp32.
// ---------------------------------------------------------------------------
__global__ __launch_bounds__(256)
void cell_k(const float* __restrict__ P, const float* __restrict__ bih,
            const float* __restrict__ bhh, float* __restrict__ c,
            unsigned short* __restrict__ hhi, unsigned short* __restrict__ hlo)
{
    const int tid = blockIdx.x * 256 + threadIdx.x;   // B*H threads
    const int b = tid >> 10;
    const int u = tid & (HH - 1);

    float gi = bih[u]          + bhh[u];
    float gf = bih[HH + u]     + bhh[HH + u];
    float gg = bih[2 * HH + u] + bhh[2 * HH + u];
    float go = bih[3 * HH + u] + bhh[3 * HH + u];

#pragma unroll
    for (int s = 0; s < KS; s++) {
        const float* ps = P + (size_t)s * (BB * NG) + (size_t)b * NG;
        gi += ps[u];
        gf += ps[HH + u];
        gg += ps[2 * HH + u];
        go += ps[3 * HH + u];
    }

    const float si = 1.0f / (1.0f + expf(-gi));
    const float sf = 1.0f / (1.0f + expf(-gf));
    const float so = 1.0f / (1.0f + expf(-go));
    const float cn = sf * c[tid] + si * tanhf(gg);
    const float hn = so * tanhf(cn);
    c[tid] = cn;
    split_bf16(hn, &hhi[tid], &hlo[tid]);
}

// ---------------------------------------------------------------------------
// logits_mfma_k: 64x64 logits tile via split-bf16 MFMA with register-prefetch
// software pipeline; argmax-partial epilogue. A (h1) and W (Wout) pre-split.
// Grid: 500 blocks x 256 thr (4 waves). Wave w -> rows [16w,16w+16).
// ---------------------------------------------------------------------------
__global__ __launch_bounds__(256)
void logits_mfma_k(const unsigned short* __restrict__ Ahi,
                   const unsigned short* __restrict__ Alo,
                   const unsigned short* __restrict__ Whi,
                   const unsigned short* __restrict__ Wlo,
                   const float* __restrict__ bout,
                   float* __restrict__ pv, int* __restrict__ pi)
{
    __shared__ unsigned short Ah[64][72], Al[64][72], Wh[64][72], Wl[64][72];
    __shared__ float rv[64][16];
    __shared__ int   ri[64][16];

    const int v0   = blockIdx.x * 64;
    const int tid  = threadIdx.x;
    const int wv   = tid >> 6;
    const int lane = tid & 63;
    const int l15  = lane & 15;
    const int q    = lane >> 4;
    const int sr   = tid >> 3;
    const int sc   = tid & 7;

    f32x4 acc[4] = {{0,0,0,0},{0,0,0,0},{0,0,0,0},{0,0,0,0}};

    uint4 rA0h, rA0l, rA1h, rA1l, rW0h, rW0l, rW1h, rW1l;

#define L_LOAD_CHUNK(kb_)                                                       \
    do {                                                                        \
        const size_t ao_ = (size_t)sr * HH + (kb_) + sc * 8;                    \
        const size_t wo_ = (size_t)(v0 + sr) * HH + (kb_) + sc * 8;             \
        const size_t s32_ = (size_t)32 * HH;                                    \
        rA0h = *(const uint4*)(Ahi + ao_);                                      \
        rA0l = *(const uint4*)(Alo + ao_);                                      \
        rA1h = *(const uint4*)(Ahi + ao_ + s32_);                               \
        rA1l = *(const uint4*)(Alo + ao_ + s32_);                               \
        rW0h = *(const uint4*)(Whi + wo_);                                      \
        rW0l = *(const uint4*)(Wlo + wo_);                                      \
        rW1h = *(const uint4*)(Whi + wo_ + s32_);                               \
        rW1l = *(const uint4*)(Wlo + wo_ + s32_);                               \
    } while (0)

    L_LOAD_CHUNK(0);
    for (int kb = 0; kb < HH; kb += 64) {
        if (kb) __syncthreads();
        *(uint4*)&Ah[sr][sc * 8]      = rA0h;
        *(uint4*)&Al[sr][sc * 8]      = rA0l;
        *(uint4*)&Ah[sr + 32][sc * 8] = rA1h;
        *(uint4*)&Al[sr + 32][sc * 8] = rA1l;
        *(uint4*)&Wh[sr][sc * 8]      = rW0h;
        *(uint4*)&Wl[sr][sc * 8]      = rW0l;
        *(uint4*)&Wh[sr + 32][sc * 8] = rW1h;
        *(uint4*)&Wl[sr + 32][sc * 8] = rW1l;
        if (kb + 64 < HH) L_LOAD_CHUNK(kb + 64);   // issue early
        __syncthreads();

#pragma unroll
        for (int ks = 0; ks < 2; ks++) {
            const int ko = ks * 32 + q * 8;
            const bf16x8 ah = *(const bf16x8*)&Ah[16 * wv + l15][ko];
            const bf16x8 al = *(const bf16x8*)&Al[16 * wv + l15][ko];
#pragma unroll
            for (int t = 0; t < 4; t++) {
                const bf16x8 bh = *(const bf16x8*)&Wh[16 * t + l15][ko];
                const bf16x8 bl = *(const bf16x8*)&Wl[16 * t + l15][ko];
                acc[t] = __builtin_amdgcn_mfma_f32_16x16x32_bf16(ah, bl, acc[t], 0, 0, 0);
                acc[t] = __builtin_amdgcn_mfma_f32_16x16x32_bf16(al, bh, acc[t], 0, 0, 0);
                acc[t] = __builtin_amdgcn_mfma_f32_16x16x32_bf16(ah, bh, acc[t], 0, 0, 0);
            }
        }
    }
#undef L_LOAD_CHUNK

    // epilogue: +bias, per-lane argmax over its 4 cols per row, then LDS reduce.
    // C/D layout (16x16): col = lane&15, row = q*4 + reg  [m89-verified]
#pragma unroll
    for (int reg = 0; reg < 4; reg++) {
        float best = -INFINITY;
        int bid = 0x7fffffff;
#pragma unroll
        for (int t = 0; t < 4; t++) {
            const int id = v0 + 16 * t + l15;
            const float v = acc[t][reg] + bout[id];
            if (v > best || (v == best && id < bid)) { best = v; bid = id; }
        }
        rv[16 * wv + q * 4 + reg][l15] = best;
        ri[16 * wv + q * 4 + reg][l15] = bid;
    }
    __syncthreads();

    if (tid < 64) {
        float best = -INFINITY;
        int bid = 0x7fffffff;
        for (int k = 0; k < 16; k++) {
            const float v = rv[tid][k];
            const int id = ri[tid][k];
            if (v > best || (v == best && id < bid)) { best = v; bid = id; }
        }
        pv[(size_t)tid * VBLK + blockIdx.x] = best;
        pi[(size_t)tid * VBLK + blockIdx.x] = bid;
    }
}

// ---------------------------------------------------------------------------
// final_k: reduce VBLK argmax partials per row -> token; gather embed row and
// emit it directly as bf16 hi/lo (the only form the gate kernel consumes).
// ---------------------------------------------------------------------------
__global__ __launch_bounds__(256)
void final_k(const float* __restrict__ pv, const int* __restrict__ pi,
             const float* __restrict__ embed, unsigned short* __restrict__ xhi,
             unsigned short* __restrict__ xlo, int* __restrict__ out, int t)
{
    __shared__ float sv[256];
    __shared__ int   si[256];
    const int b = blockIdx.x;
    const int tid = threadIdx.x;

    float best = -INFINITY;
    int bid = 0x7fffffff;
    for (int k = tid; k < VBLK; k += 256) {
        float v = pv[(size_t)b * VBLK + k];
        int id = pi[(size_t)b * VBLK + k];
        if (v > best || (v == best && id < bid)) { best = v; bid = id; }
    }
    sv[tid] = best; si[tid] = bid;
    __syncthreads();
    for (int s = 128; s > 0; s >>= 1) {
        if (tid < s) {
            float v = sv[tid + s]; int id = si[tid + s];
            if (v > sv[tid] || (v == sv[tid] && id < si[tid])) { sv[tid] = v; si[tid] = id; }
        }
        __syncthreads();
    }
    const int pred = si[0];
    if (tid == 0) out[(size_t)b * TT + t] = pred;
    for (int d = tid; d < DD; d += 256) {
        const float v = embed[(size_t)pred * DD + d];
        split_bf16(v, &xhi[(size_t)b * DD + d], &xlo[(size_t)b * DD + d]);
    }
}

// ---------------------------------------------------------------------------
extern "C" void kernel_launch(void* const* d_in, const int* in_sizes, int n_in,
                              void* d_out, int out_size, void* d_ws, size_t ws_size,
                              hipStream_t stream)
{
    const float* features = (const float*)d_in[0];
    const float* embed    = (const float*)d_in[1];
    const float* Wih0     = (const float*)d_in[2];
    const float* Whh0     = (const float*)d_in[3];
    const float* bih0     = (const float*)d_in[4];
    const float* bhh0     = (const float*)d_in[5];
    const float* Wih1     = (const float*)d_in[6];
    const float* Whh1     = (const float*)d_in[7];
    const float* bih1     = (const float*)d_in[8];
    const float* bhh1     = (const float*)d_in[9];
    const float* Wout     = (const float*)d_in[10];
    const float* bout     = (const float*)d_in[11];
    int* out = (int*)d_out;

    // workspace layout (all offsets 16B-aligned)
    float* ws = (float*)d_ws;
    float* c0 = ws;                                            // B*H fp32
    float* c1 = c0 + BB * HH;
    unsigned short* hhi0 = (unsigned short*)(c1 + BB * HH);    // B*H bf16 each
    unsigned short* hlo0 = hhi0 + BB * HH;
    unsigned short* hhi1 = hlo0 + BB * HH;
    unsigned short* hlo1 = hhi1 + BB * HH;
    unsigned short* xhi  = hlo1 + BB * HH;                     // B*D bf16 each
    unsigned short* xlo  = xhi + BB * DD;
    float* part = (float*)(xlo + BB * DD);                     // KS*B*NG fp32
    float* pv   = part + (size_t)KS * BB * NG;                 // B*VBLK
    int*   pi   = (int*)(pv + BB * VBLK);                      // B*VBLK
    unsigned short* wih0h = (unsigned short*)(pi + BB * VBLK); // NG*D each
    unsigned short* wih0l = wih0h + (size_t)NG * DD;
    unsigned short* whh0h = wih0l + (size_t)NG * DD;           // NG*H each
    unsigned short* whh0l = whh0h + (size_t)NG * HH;
    unsigned short* wih1h = whh0l + (size_t)NG * HH;
    unsigned short* wih1l = wih1h + (size_t)NG * HH;
    unsigned short* whh1h = wih1l + (size_t)NG * HH;
    unsigned short* whh1l = whh1h + (size_t)NG * HH;
    unsigned short* wouth = whh1l + (size_t)NG * HH;           // V*H each
    unsigned short* woutl = wouth + (size_t)VV * HH;

    // zero c0,c1 + all h hi/lo splits (contiguous, 1 MiB total)
    hipMemsetAsync(c0, 0, (size_t)2 * BB * HH * sizeof(float)
                        + (size_t)4 * BB * HH * sizeof(unsigned short), stream);

    const dim3 blk(256);
    const dim3 ggates(NG / 64, KS);
    const dim3 gcell(BB * HH / 256);
    const dim3 glog(VBLK);
    const dim3 gfin(BB);

    // one-time per call: pre-split all constant operands to bf16 hi/lo
    {
        auto gs = [](int n4) { int g = (n4 + 255) / 256; return dim3(g > 2048 ? 2048 : g); };
        split_k<<<gs(NG * DD / 4), blk, 0, stream>>>(Wih0, wih0h, wih0l, NG * DD / 4);
        split_k<<<gs(NG * HH / 4), blk, 0, stream>>>(Whh0, whh0h, whh0l, NG * HH / 4);
        split_k<<<gs(NG * HH / 4), blk, 0, stream>>>(Wih1, wih1h, wih1l, NG * HH / 4);
        split_k<<<gs(NG * HH / 4), blk, 0, stream>>>(Whh1, whh1h, whh1l, NG * HH / 4);
        split_k<<<gs(VV * HH / 4), blk, 0, stream>>>(Wout, wouth, woutl, VV * HH / 4);
        split_k<<<gs(BB * DD / 4), blk, 0, stream>>>(features, xhi, xlo, BB * DD / 4);
    }

    for (int t = 0; t < TT; t++) {
        // layer 0: gates = x@Wih0^T + h0@Whh0^T (fused), then cell
        gates_mfma_k<<<ggates, blk, 0, stream>>>(xhi, xlo, DD, hhi0, hlo0,
                                                 wih0h, wih0l, whh0h, whh0l, part);
        cell_k<<<gcell, blk, 0, stream>>>(part, bih0, bhh0, c0, hhi0, hlo0);
        // layer 1
        gates_mfma_k<<<ggates, blk, 0, stream>>>(hhi0, hlo0, HH, hhi1, hlo1,
                                                 wih1h, wih1l, whh1h, whh1l, part);
        cell_k<<<gcell, blk, 0, stream>>>(part, bih1, bhh1, c1, hhi1, hlo1);
        // output projection (split-bf16 MFMA) + argmax partials
        logits_mfma_k<<<glog, blk, 0, stream>>>(hhi1, hlo1, wouth, woutl, bout, pv, pi);
        // argmax reduce + token write + embedding gather (pre-split)
        final_k<<<gfin, blk, 0, stream>>>(pv, pi, embed, xhi, xlo, out, t);
    }
}